// Round 8
// baseline (96.153 us; speedup 1.0000x reference)
//
#include <hip/hip_runtime.h>
#include <hip/hip_bf16.h>

#define ENC 15
#define HID 128
#define RES 16

typedef __attribute__((ext_vector_type(4))) float f32x4;
typedef __attribute__((ext_vector_type(8))) short s16x8;
typedef __attribute__((ext_vector_type(4))) short s16x4;

static __device__ __forceinline__ short f2bf(float v) {
    __hip_bfloat16 h = __float2bfloat16(v);
    return __builtin_bit_cast(short, h);
}

// ---- weight prep: fp32 -> bf16 (zero-padded) into workspace ----
// ws layout (bf16 elements):
//   W1b [128][32]  @ 0      (k padded 18->32)
//   W2b [128][128] @ 4096
//   W3b [16][128]  @ 20480  (rows padded 3->16)
__global__ void NSC_prep_kernel(const float* __restrict__ W1,
                                const float* __restrict__ W2,
                                const float* __restrict__ W3,
                                __hip_bfloat16* __restrict__ ws) {
    int t = blockIdx.x * 256 + threadIdx.x;
    if (t < 4096) {
        int row = t >> 5, k = t & 31;
        float v = (k < 18) ? W1[row * 18 + k] : 0.0f;
        ws[t] = __float2bfloat16(v);
    } else if (t < 20480) {
        ws[t] = __float2bfloat16(W2[t - 4096]);
    } else if (t < 22528) {
        int i = t - 20480;
        int row = i >> 7, k = i & 127;
        float v = (row < 3) ? W3[row * 128 + k] : 0.0f;
        ws[t] = __float2bfloat16(v);
    }
}

// One block = 4 waves / 256 threads (the only proven block shape), covering
// HALF a complex: 128 pixels, 32 px per wave (n=2) — px-per-wave proven in
// r3/r4. H-tile 32 KB -> 4 blocks/CU (vs 2): doubles independent wave
// streams per SIMD to fill the ~60% no-issue stall time seen in r7.
// All GEMMs swapped: C[feature][pixel] = W[feature][k] * H^T[k][pixel].
// LDS: one 32 KB buffer, time-shared:
//   X phase : bf16 [128 px][80 B rows], swizzle byte ^= ((px^(px>>3))&3)<<4
//   H phase : bf16 [128 px][128 f], row 256 B, swizzle byte ^= (px&7)<<4
//   outL    : float [128][5] at base (after H reads done)
// Cross-wave LDS (X rows, outL) is ordered by the existing real barriers.
__global__ __launch_bounds__(256, 4)
void NSC_59133109732095_kernel(
    const float* __restrict__ points,
    const float* __restrict__ encodings,
    const float* __restrict__ b1,
    const float* __restrict__ b2,
    const float* __restrict__ b3,
    const int*   __restrict__ complexes,
    const __hip_bfloat16* __restrict__ ws,
    float* __restrict__ out0,
    float* __restrict__ out1,
    float* __restrict__ out2)
{
    __shared__ __align__(16) char smem[32768];
    char*  Xb   = smem;           // [128][80 B]
    char*  Hb   = smem;           // [128][256 B]
    float* outL = (float*)smem;   // [128][5]

    const int blk  = blockIdx.x;
    const int c    = blk >> 1;
    const int half = blk & 1;     // pixels [half*128, half*128+128)
    const int tid  = threadIdx.x;
    const int lane = tid & 63;
    const int wv   = tid >> 6;    // wave 0..3 -> block-local px [wv*32, wv*32+32)
    const int wb   = wv * 32;
    const int g    = lane >> 4;   // k-group 0..3
    const int r16  = lane & 15;

    const __hip_bfloat16* W1b = ws;
    const __hip_bfloat16* W2b = ws + 4096;
    const __hip_bfloat16* W3b = ws + 20480;

    // ---- phase 0: bilinear interp; threads 0..127 own block-local px = tid ----
    float p[3] = {0.f, 0.f, 0.f};
    if (tid < 128) {
        const int px = half * 128 + tid;      // pixel within complex
        const int pi = px >> 4, pj = px & 15;
        const float ui = (float)pi * (1.0f / 15.0f);
        const float uj = (float)pj * (1.0f / 15.0f);
        const float w00 = (1.0f - ui) * (1.0f - uj), w01 = (1.0f - ui) * uj;
        const float w10 = ui * (1.0f - uj),          w11 = ui * uj;
        const int v0 = complexes[c * 4 + 0], v1 = complexes[c * 4 + 1];
        const int v2 = complexes[c * 4 + 2], v3 = complexes[c * 4 + 3];

        #pragma unroll
        for (int f = 0; f < 3; ++f)
            p[f] = w00 * points[v0 * 3 + f] + w01 * points[v1 * 3 + f]
                 + w10 * points[v2 * 3 + f] + w11 * points[v3 * 3 + f];

        float Xf[18];
        #pragma unroll
        for (int k = 0; k < ENC; ++k)
            Xf[k] = w00 * encodings[v0 * ENC + k] + w01 * encodings[v1 * ENC + k]
                  + w10 * encodings[v2 * ENC + k] + w11 * encodings[v3 * ENC + k];
        #pragma unroll
        for (int f = 0; f < 3; ++f) Xf[ENC + f] = __sinf(p[f]);

        // write X row (32 bf16, zero-padded), stride 80, r7 swizzle
        #pragma unroll
        for (int t = 0; t < 4; ++t) {
            s16x8 v;
            #pragma unroll
            for (int i = 0; i < 8; ++i) {
                int k = t * 8 + i;
                v[i] = (k < 18) ? f2bf(Xf[k]) : (short)0;
            }
            *(s16x8*)(Xb + tid * 80 + ((t * 16) ^ (((tid ^ (tid >> 3)) & 3) << 4))) = v;
        }
    }
    __syncthreads();   // A: X visible (cross-wave)

    // ---- layer 1: [128 j] x [32 k] -> acc[j][px], bias-initialized ----
    f32x4 acc[8][2];
    #pragma unroll
    for (int m = 0; m < 8; ++m) {
        f32x4 bv = *(const f32x4*)(b1 + m * 16 + g * 4);
        #pragma unroll
        for (int n = 0; n < 2; ++n) acc[m][n] = bv;
    }
    {
        s16x8 a1[8];
        #pragma unroll
        for (int m = 0; m < 8; ++m)
            a1[m] = *(const s16x8*)(W1b + (m * 16 + r16) * 32 + g * 8);
        s16x8 bx[2];
        #pragma unroll
        for (int n = 0; n < 2; ++n) {
            int px = wb + n * 16 + r16;
            bx[n] = *(const s16x8*)(Xb + px * 80 + ((g * 16) ^ (((px ^ (px >> 3)) & 3) << 4)));
        }
        #pragma unroll
        for (int m = 0; m < 8; ++m)
            #pragma unroll
            for (int n = 0; n < 2; ++n)
                acc[m][n] = __builtin_amdgcn_mfma_f32_16x16x32_bf16(a1[m], bx[n], acc[m][n], 0, 0, 0);
    }
    __syncthreads();   // B: X reads done, region may become H

    // sin -> bf16 -> H (h1)
    #pragma unroll
    for (int m = 0; m < 8; ++m)
        #pragma unroll
        for (int n = 0; n < 2; ++n) {
            s16x4 hv;
            #pragma unroll
            for (int r = 0; r < 4; ++r) hv[r] = f2bf(__sinf(acc[m][n][r]));
            int px = wb + n * 16 + r16;
            *(s16x4*)(Hb + px * 256 + ((m * 32 + g * 8) ^ ((px & 7) << 4))) = hv;
        }
    __syncthreads();   // C: h1 visible

    // ---- layer 2: [128 j] x [128 k], batched A-loads per ks ----
    #pragma unroll
    for (int m = 0; m < 8; ++m) {
        f32x4 bv = *(const f32x4*)(b2 + m * 16 + g * 4);
        #pragma unroll
        for (int n = 0; n < 2; ++n) acc[m][n] = bv;
    }
    #pragma unroll
    for (int ks = 0; ks < 4; ++ks) {
        s16x8 hb[2];
        #pragma unroll
        for (int n = 0; n < 2; ++n) {
            int px = wb + n * 16 + r16;
            hb[n] = *(const s16x8*)(Hb + px * 256 + ((ks * 64 + g * 16) ^ ((px & 7) << 4)));
        }
        s16x8 a2[8];
        #pragma unroll
        for (int m = 0; m < 8; ++m)
            a2[m] = *(const s16x8*)(W2b + (m * 16 + r16) * 128 + ks * 32 + g * 8);
        #pragma unroll
        for (int m = 0; m < 8; ++m)
            #pragma unroll
            for (int n = 0; n < 2; ++n)
                acc[m][n] = __builtin_amdgcn_mfma_f32_16x16x32_bf16(a2[m], hb[n], acc[m][n], 0, 0, 0);
    }
    __syncthreads();   // D: h1 reads done

    // sin -> bf16 -> H (h2 overwrites h1)
    #pragma unroll
    for (int m = 0; m < 8; ++m)
        #pragma unroll
        for (int n = 0; n < 2; ++n) {
            s16x4 hv;
            #pragma unroll
            for (int r = 0; r < 4; ++r) hv[r] = f2bf(__sinf(acc[m][n][r]));
            int px = wb + n * 16 + r16;
            *(s16x4*)(Hb + px * 256 + ((m * 32 + g * 8) ^ ((px & 7) << 4))) = hv;
        }
    __syncthreads();   // E: h2 visible

    // ---- layer 3: [16 j (3 used)] x [128 k] ----
    f32x4 acc3[2];
    acc3[0] = f32x4{0.f, 0.f, 0.f, 0.f};
    acc3[1] = f32x4{0.f, 0.f, 0.f, 0.f};
    #pragma unroll
    for (int ks = 0; ks < 4; ++ks) {
        s16x8 a3 = *(const s16x8*)(W3b + r16 * 128 + ks * 32 + g * 8);
        #pragma unroll
        for (int n = 0; n < 2; ++n) {
            int px = wb + n * 16 + r16;
            s16x8 hb = *(const s16x8*)(Hb + px * 256 + ((ks * 64 + g * 16) ^ ((px & 7) << 4)));
            acc3[n] = __builtin_amdgcn_mfma_f32_16x16x32_bf16(a3, hb, acc3[n], 0, 0, 0);
        }
    }
    __syncthreads();   // F: h2 reads done, region may become outL

    if (g == 0) {      // lanes holding j = 0..3 (regs), j<3 valid
        #pragma unroll
        for (int n = 0; n < 2; ++n) {
            int px = wb + n * 16 + r16;
            outL[px * 5 + 0] = acc3[n][0];
            outL[px * 5 + 1] = acc3[n][1];
            outL[px * 5 + 2] = acc3[n][2];
        }
    }
    __syncthreads();   // G: outL visible (cross-wave)

    // ---- epilogue: threads 0..127 own block-local pixel tid ----
    if (tid < 128) {
        float x0 = outL[tid * 5 + 0] + b3[0];
        float x1 = outL[tid * 5 + 1] + b3[1];
        float x2 = outL[tid * 5 + 2] + b3[2];
        const int base = (c * 256 + half * 128 + tid) * 3;
        out0[base + 0] = p[0] + x0;
        out0[base + 1] = p[1] + x1;
        out0[base + 2] = p[2] + x2;
        out1[base + 0] = x0;
        out1[base + 1] = x1;
        out1[base + 2] = x2;
    }
    if (blk == 0 && tid == 0) out2[0] = 1.0f;
}

extern "C" void kernel_launch(void* const* d_in, const int* in_sizes, int n_in,
                              void* d_out, int out_size, void* d_ws, size_t ws_size,
                              hipStream_t stream) {
    const float* points    = (const float*)d_in[0];
    const float* encodings = (const float*)d_in[1];
    const float* W1        = (const float*)d_in[2];
    const float* b1        = (const float*)d_in[3];
    const float* W2        = (const float*)d_in[4];
    const float* b2        = (const float*)d_in[5];
    const float* W3        = (const float*)d_in[6];
    const float* b3        = (const float*)d_in[7];
    const int*   complexes = (const int*)d_in[8];

    const int C  = in_sizes[8] / 4;          // 2048
    const int N3 = C * RES * RES * 3;        // 1,572,864

    float* out0 = (float*)d_out;
    float* out1 = out0 + N3;
    float* out2 = out1 + N3;

    __hip_bfloat16* ws = (__hip_bfloat16*)d_ws;  // needs 45056 B

    NSC_prep_kernel<<<88, 256, 0, stream>>>(W1, W2, W3, ws);
    NSC_59133109732095_kernel<<<C * 2, 256, 0, stream>>>(
        points, encodings, b1, b2, b3, complexes, ws, out0, out1, out2);
}

// Round 9
// 61.344 us; speedup vs baseline: 1.5674x; 1.5674x over previous
//
#include <hip/hip_runtime.h>
#include <hip/hip_bf16.h>

#define ENC 15
#define HID 128
#define RES 16

typedef __attribute__((ext_vector_type(4))) float f32x4;
typedef __attribute__((ext_vector_type(8))) short s16x8;
typedef __attribute__((ext_vector_type(4))) short s16x4;

static __device__ __forceinline__ short f2bf(float v) {
    __hip_bfloat16 h = __float2bfloat16(v);
    return __builtin_bit_cast(short, h);
}

// Wave-local LDS fence: all our LDS dependencies are wave-private by
// construction, so a full s_barrier is unnecessary. "memory" clobber keeps
// the compiler from reordering LDS ops across it; sched_barrier(0) stops the
// backend scheduler from hoisting non-memory ops past the waitcnt (rule #18).
#define WAVE_FENCE() do { \
    asm volatile("s_waitcnt lgkmcnt(0)" ::: "memory"); \
    __builtin_amdgcn_sched_barrier(0); \
} while (0)

// ---- weight prep: fp32 -> bf16 (zero-padded) into workspace ----
// ws layout (bf16 elements):
//   W1b [128][32]  @ 0      (k padded 18->32)
//   W2b [128][128] @ 4096
//   W3b [16][128]  @ 20480  (rows padded 3->16)
__global__ void NSC_prep_kernel(const float* __restrict__ W1,
                                const float* __restrict__ W2,
                                const float* __restrict__ W3,
                                __hip_bfloat16* __restrict__ ws) {
    int t = blockIdx.x * 256 + threadIdx.x;
    if (t < 4096) {
        int row = t >> 5, k = t & 31;
        float v = (k < 18) ? W1[row * 18 + k] : 0.0f;
        ws[t] = __float2bfloat16(v);
    } else if (t < 20480) {
        ws[t] = __float2bfloat16(W2[t - 4096]);
    } else if (t < 22528) {
        int i = t - 20480;
        int row = i >> 7, k = i & 127;
        float v = (row < 3) ? W3[row * 128 + k] : 0.0f;
        ws[t] = __float2bfloat16(v);
    }
}

// One block = one complex = 256 pixels, 4 waves (the proven r2/r7 shape) —
// but with ZERO s_barriers. Every LDS row is wave-private:
//   - H tile rows px*256 naturally partition into per-wave 16 KB quadrants.
//   - X tile rows are RELOCATED inside the owning wave's quadrant:
//       Xrow(px) = (px>>6)*16384 + (px&63)*80   (max 5104 < 16384, no overlap
//       with other waves; overlaps own H rows only -> ordered by fences).
//   - outL is GONE: layer-3 outputs reach their owner thread via 3 __shfl
//     (outputs for pixel-tile n live on lanes g=0; owner thread has g==n).
// So barriers degrade to wave-local s_waitcnt fences and the block's 4 waves
// free-run at different phases, interleaving VALU/MFMA/LDS across waves.
// All GEMMs swapped: C[feature][pixel] = W[feature][k] * H^T[k][pixel].
// Arithmetic is byte-identical to r7 (absmax canary: 0.015625 exactly).
__global__ __launch_bounds__(256, 2)
void NSC_59133109732095_kernel(
    const float* __restrict__ points,
    const float* __restrict__ encodings,
    const float* __restrict__ b1,
    const float* __restrict__ b2,
    const float* __restrict__ b3,
    const int*   __restrict__ complexes,
    const __hip_bfloat16* __restrict__ ws,
    float* __restrict__ out0,
    float* __restrict__ out1,
    float* __restrict__ out2)
{
    __shared__ __align__(16) char smem[65536];
    char* Hb = smem;   // H rows: px*256 + swizzle
    char* Xb = smem;   // X rows: (px>>6)*16384 + (px&63)*80 + swizzle

    const int c    = blockIdx.x;
    const int tid  = threadIdx.x;
    const int lane = tid & 63;
    const int wv   = tid >> 6;    // wave 0..3 -> pixels [wv*64, wv*64+64)
    const int g    = lane >> 4;   // k-group 0..3
    const int r16  = lane & 15;

    const __hip_bfloat16* W1b = ws;
    const __hip_bfloat16* W2b = ws + 4096;
    const __hip_bfloat16* W3b = ws + 20480;

    // ---- phase 0: per-thread bilinear interp, pixel = tid ----
    const int pi = tid >> 4, pj = tid & 15;
    const float ui = (float)pi * (1.0f / 15.0f);
    const float uj = (float)pj * (1.0f / 15.0f);
    const float w00 = (1.0f - ui) * (1.0f - uj), w01 = (1.0f - ui) * uj;
    const float w10 = ui * (1.0f - uj),          w11 = ui * uj;
    const int v0 = complexes[c * 4 + 0], v1 = complexes[c * 4 + 1];
    const int v2 = complexes[c * 4 + 2], v3 = complexes[c * 4 + 3];

    float p[3];
    #pragma unroll
    for (int f = 0; f < 3; ++f)
        p[f] = w00 * points[v0 * 3 + f] + w01 * points[v1 * 3 + f]
             + w10 * points[v2 * 3 + f] + w11 * points[v3 * 3 + f];

    float Xf[18];
    #pragma unroll
    for (int k = 0; k < ENC; ++k)
        Xf[k] = w00 * encodings[v0 * ENC + k] + w01 * encodings[v1 * ENC + k]
              + w10 * encodings[v2 * ENC + k] + w11 * encodings[v3 * ENC + k];
    #pragma unroll
    for (int f = 0; f < 3; ++f) Xf[ENC + f] = __sinf(p[f]);

    // write X row (32 bf16, zero-padded) into own wave's quadrant
    #pragma unroll
    for (int t = 0; t < 4; ++t) {
        s16x8 v;
        #pragma unroll
        for (int i = 0; i < 8; ++i) {
            int k = t * 8 + i;
            v[i] = (k < 18) ? f2bf(Xf[k]) : (short)0;
        }
        *(s16x8*)(Xb + wv * 16384 + (tid & 63) * 80
                     + ((t * 16) ^ (((tid ^ (tid >> 3)) & 3) << 4))) = v;
    }
    WAVE_FENCE();   // A: own wave's X writes complete

    // ---- layer 1: [128 j] x [32 k] -> acc[j][px], bias-initialized ----
    f32x4 acc[8][4];
    #pragma unroll
    for (int m = 0; m < 8; ++m) {
        f32x4 bv = *(const f32x4*)(b1 + m * 16 + g * 4);
        #pragma unroll
        for (int n = 0; n < 4; ++n) acc[m][n] = bv;
    }
    {
        s16x8 a1[8];
        #pragma unroll
        for (int m = 0; m < 8; ++m)
            a1[m] = *(const s16x8*)(W1b + (m * 16 + r16) * 32 + g * 8);
        s16x8 bx[4];
        #pragma unroll
        for (int n = 0; n < 4; ++n) {
            int px = wv * 64 + n * 16 + r16;
            bx[n] = *(const s16x8*)(Xb + wv * 16384 + (px & 63) * 80
                        + ((g * 16) ^ (((px ^ (px >> 3)) & 3) << 4)));
        }
        #pragma unroll
        for (int m = 0; m < 8; ++m)
            #pragma unroll
            for (int n = 0; n < 4; ++n)
                acc[m][n] = __builtin_amdgcn_mfma_f32_16x16x32_bf16(a1[m], bx[n], acc[m][n], 0, 0, 0);
    }
    WAVE_FENCE();   // B: X reads done -> region may become H (own quadrant)

    // sin -> bf16 -> H (h1)
    #pragma unroll
    for (int m = 0; m < 8; ++m)
        #pragma unroll
        for (int n = 0; n < 4; ++n) {
            s16x4 hv;
            #pragma unroll
            for (int r = 0; r < 4; ++r) hv[r] = f2bf(__sinf(acc[m][n][r]));
            int px = wv * 64 + n * 16 + r16;
            *(s16x4*)(Hb + px * 256 + ((m * 32 + g * 8) ^ ((px & 7) << 4))) = hv;
        }
    WAVE_FENCE();   // C: h1 visible (own wave's rows)

    // ---- layer 2: [128 j] x [128 k], batched A-loads per ks ----
    #pragma unroll
    for (int m = 0; m < 8; ++m) {
        f32x4 bv = *(const f32x4*)(b2 + m * 16 + g * 4);
        #pragma unroll
        for (int n = 0; n < 4; ++n) acc[m][n] = bv;
    }
    #pragma unroll
    for (int ks = 0; ks < 4; ++ks) {
        s16x8 hb[4];
        #pragma unroll
        for (int n = 0; n < 4; ++n) {
            int px = wv * 64 + n * 16 + r16;
            hb[n] = *(const s16x8*)(Hb + px * 256 + ((ks * 64 + g * 16) ^ ((px & 7) << 4)));
        }
        s16x8 a2[8];
        #pragma unroll
        for (int m = 0; m < 8; ++m)
            a2[m] = *(const s16x8*)(W2b + (m * 16 + r16) * 128 + ks * 32 + g * 8);
        #pragma unroll
        for (int m = 0; m < 8; ++m)
            #pragma unroll
            for (int n = 0; n < 4; ++n)
                acc[m][n] = __builtin_amdgcn_mfma_f32_16x16x32_bf16(a2[m], hb[n], acc[m][n], 0, 0, 0);
    }
    WAVE_FENCE();   // D: h1 reads done

    // sin -> bf16 -> H (h2 overwrites h1)
    #pragma unroll
    for (int m = 0; m < 8; ++m)
        #pragma unroll
        for (int n = 0; n < 4; ++n) {
            s16x4 hv;
            #pragma unroll
            for (int r = 0; r < 4; ++r) hv[r] = f2bf(__sinf(acc[m][n][r]));
            int px = wv * 64 + n * 16 + r16;
            *(s16x4*)(Hb + px * 256 + ((m * 32 + g * 8) ^ ((px & 7) << 4))) = hv;
        }
    WAVE_FENCE();   // E: h2 visible

    // ---- layer 3: [16 j (3 used)] x [128 k] ----
    f32x4 acc3[4];
    #pragma unroll
    for (int n = 0; n < 4; ++n) acc3[n] = f32x4{0.f, 0.f, 0.f, 0.f};
    #pragma unroll
    for (int ks = 0; ks < 4; ++ks) {
        s16x8 a3 = *(const s16x8*)(W3b + r16 * 128 + ks * 32 + g * 8);
        #pragma unroll
        for (int n = 0; n < 4; ++n) {
            int px = wv * 64 + n * 16 + r16;
            s16x8 hb = *(const s16x8*)(Hb + px * 256 + ((ks * 64 + g * 16) ^ ((px & 7) << 4)));
            acc3[n] = __builtin_amdgcn_mfma_f32_16x16x32_bf16(a3, hb, acc3[n], 0, 0, 0);
        }
    }

    // ---- epilogue, no LDS: outputs for pixel-tile n live on lanes g==0
    // (regs j=0..2, col r16). Thread tid's own pixel is tile n == g, col r16.
    // __shfl from lane r16 broadcasts g=0's values to all g-groups; the g==n
    // thread stores its OWN pixel (p[] already local).
    {
        const float b30 = b3[0], b31 = b3[1], b32 = b3[2];
        #pragma unroll
        for (int n = 0; n < 4; ++n) {
            float x0 = __shfl(acc3[n][0], r16);
            float x1 = __shfl(acc3[n][1], r16);
            float x2 = __shfl(acc3[n][2], r16);
            if (g == n) {
                x0 += b30; x1 += b31; x2 += b32;
                const int base = (c * 256 + tid) * 3;
                out0[base + 0] = p[0] + x0;
                out0[base + 1] = p[1] + x1;
                out0[base + 2] = p[2] + x2;
                out1[base + 0] = x0;
                out1[base + 1] = x1;
                out1[base + 2] = x2;
            }
        }
    }
    if (c == 0 && tid == 0) out2[0] = 1.0f;
}

extern "C" void kernel_launch(void* const* d_in, const int* in_sizes, int n_in,
                              void* d_out, int out_size, void* d_ws, size_t ws_size,
                              hipStream_t stream) {
    const float* points    = (const float*)d_in[0];
    const float* encodings = (const float*)d_in[1];
    const float* W1        = (const float*)d_in[2];
    const float* b1        = (const float*)d_in[3];
    const float* W2        = (const float*)d_in[4];
    const float* b2        = (const float*)d_in[5];
    const float* W3        = (const float*)d_in[6];
    const float* b3        = (const float*)d_in[7];
    const int*   complexes = (const int*)d_in[8];

    const int C  = in_sizes[8] / 4;          // 2048
    const int N3 = C * RES * RES * 3;        // 1,572,864

    float* out0 = (float*)d_out;
    float* out1 = out0 + N3;
    float* out2 = out1 + N3;

    __hip_bfloat16* ws = (__hip_bfloat16*)d_ws;  // needs 45056 B

    NSC_prep_kernel<<<88, 256, 0, stream>>>(W1, W2, W3, ws);
    NSC_59133109732095_kernel<<<C, 256, 0, stream>>>(
        points, encodings, b1, b2, b3, complexes, ws, out0, out1, out2);
}

// Round 10
// 59.109 us; speedup vs baseline: 1.6267x; 1.0378x over previous
//
#include <hip/hip_runtime.h>
#include <hip/hip_bf16.h>

#define ENC 15

typedef __attribute__((ext_vector_type(4))) float f32x4;
typedef __attribute__((ext_vector_type(8))) short s16x8;
typedef __attribute__((ext_vector_type(4))) short s16x4;

static __device__ __forceinline__ short f2bf(float v) {
    __hip_bfloat16 h = __float2bfloat16(v);
    return __builtin_bit_cast(short, h);
}

// Wave-local LDS fence (r9-proven): all LDS deps are wave-private.
#define WAVE_FENCE() do { \
    asm volatile("s_waitcnt lgkmcnt(0)" ::: "memory"); \
    __builtin_amdgcn_sched_barrier(0); \
} while (0)

// ---- weight prep: fp32 -> bf16 into workspace ----
// ws layout (bf16): W1b [128][32] @ 0 (k padded 18->32), W2b [128][128] @ 4096.
// W3 is consumed as fp32 directly by the main kernel (in-register layer 3).
__global__ void NSC_prep_kernel(const float* __restrict__ W1,
                                const float* __restrict__ W2,
                                __hip_bfloat16* __restrict__ ws) {
    int t = blockIdx.x * 256 + threadIdx.x;
    if (t < 4096) {
        int row = t >> 5, k = t & 31;
        float v = (k < 18) ? W1[row * 18 + k] : 0.0f;
        ws[t] = __float2bfloat16(v);
    } else if (t < 20480) {
        ws[t] = __float2bfloat16(W2[t - 4096]);
    }
}

// One block = one complex = 256 px, 4 waves, r9 fence machinery (no barriers).
// ks-INTERLEAVED pipeline: per k-slice ks (32 features of h1):
//   sin+pack L1 pair (VALU)  ->  write 16 KB rotating LDS slice  ->  read
//   B-frags  ->  issue L1-MFMA[ks+1]  ->  32 L2-MFMA[ks]
// so sin[ks+1] overlaps L2[ks]'s MFMA pipe time (separate pipes, m114).
// Layer 3 is in-register dots + shfl_xor reduce: h2 never touches LDS.
// LDS: [256 px][64 B] single tile (X, then h1 slices), swizzle (px&3)<<4.
// Layers 1-2 arithmetic bit-identical to r9.
__global__ __launch_bounds__(256, 2)
void NSC_59133109732095_kernel(
    const float* __restrict__ points,
    const float* __restrict__ encodings,
    const float* __restrict__ b1,
    const float* __restrict__ b2,
    const float* __restrict__ W3,
    const float* __restrict__ b3,
    const int*   __restrict__ complexes,
    const __hip_bfloat16* __restrict__ ws,
    float* __restrict__ out0,
    float* __restrict__ out1,
    float* __restrict__ out2)
{
    __shared__ __align__(16) char smem[16384];   // [256 rows][64 B]

    const int c    = blockIdx.x;
    const int tid  = threadIdx.x;
    const int lane = tid & 63;
    const int wv   = tid >> 6;    // wave -> pixels [wv*64, wv*64+64)
    const int g    = lane >> 4;   // k-group 0..3
    const int r16  = lane & 15;

    const __hip_bfloat16* W1b = ws;
    const __hip_bfloat16* W2b = ws + 4096;

    // ---- phase 0: per-thread bilinear interp, pixel = tid (r9-identical) ----
    const int pi = tid >> 4, pj = tid & 15;
    const float ui = (float)pi * (1.0f / 15.0f);
    const float uj = (float)pj * (1.0f / 15.0f);
    const float w00 = (1.0f - ui) * (1.0f - uj), w01 = (1.0f - ui) * uj;
    const float w10 = ui * (1.0f - uj),          w11 = ui * uj;
    const int v0 = complexes[c * 4 + 0], v1 = complexes[c * 4 + 1];
    const int v2 = complexes[c * 4 + 2], v3 = complexes[c * 4 + 3];

    float p[3];
    #pragma unroll
    for (int f = 0; f < 3; ++f)
        p[f] = w00 * points[v0 * 3 + f] + w01 * points[v1 * 3 + f]
             + w10 * points[v2 * 3 + f] + w11 * points[v3 * 3 + f];

    float Xf[18];
    #pragma unroll
    for (int k = 0; k < ENC; ++k)
        Xf[k] = w00 * encodings[v0 * ENC + k] + w01 * encodings[v1 * ENC + k]
              + w10 * encodings[v2 * ENC + k] + w11 * encodings[v3 * ENC + k];
    #pragma unroll
    for (int f = 0; f < 3; ++f) Xf[ENC + f] = __sinf(p[f]);

    // write X row (32 bf16 zero-padded) into own row tid, 64 B rows
    #pragma unroll
    for (int ch = 0; ch < 4; ++ch) {
        s16x8 v;
        #pragma unroll
        for (int i = 0; i < 8; ++i) {
            int k = ch * 8 + i;
            v[i] = (k < 18) ? f2bf(Xf[k]) : (short)0;
        }
        *(s16x8*)(smem + tid * 64 + ((ch * 16) ^ ((tid & 3) << 4))) = v;
    }
    WAVE_FENCE();   // X visible (wave-private rows)

    // ---- read X B-frags ONCE into persistent registers ----
    s16x8 bx[4];
    #pragma unroll
    for (int n = 0; n < 4; ++n) {
        int px = wv * 64 + n * 16 + r16;
        bx[n] = *(const s16x8*)(smem + px * 64 + ((g * 16) ^ ((px & 3) << 4)));
    }

    // ---- init layer-2 accumulators with biases ----
    f32x4 acc2[8][4];
    #pragma unroll
    for (int m = 0; m < 8; ++m) {
        f32x4 bv = *(const f32x4*)(b2 + m * 16 + g * 4);
        #pragma unroll
        for (int n = 0; n < 4; ++n) acc2[m][n] = bv;
    }

    // ---- prologue: layer-1 pair for ks=0 (tiles m=0,1) ----
    f32x4 accp[2][4];
    #pragma unroll
    for (int mm = 0; mm < 2; ++mm) {
        f32x4 bv = *(const f32x4*)(b1 + mm * 16 + g * 4);
        #pragma unroll
        for (int n = 0; n < 4; ++n) accp[mm][n] = bv;
        s16x8 a1 = *(const s16x8*)(W1b + (mm * 16 + r16) * 32 + g * 8);
        #pragma unroll
        for (int n = 0; n < 4; ++n)
            accp[mm][n] = __builtin_amdgcn_mfma_f32_16x16x32_bf16(a1, bx[n], accp[mm][n], 0, 0, 0);
    }

    // ---- main ks pipeline ----
    #pragma unroll
    for (int ks = 0; ks < 4; ++ks) {
        // sin+pack the current L1 pair (h1 features ks*32 .. ks*32+31)
        s16x4 hv[2][4];
        #pragma unroll
        for (int mm = 0; mm < 2; ++mm)
            #pragma unroll
            for (int n = 0; n < 4; ++n)
                #pragma unroll
                for (int r = 0; r < 4; ++r)
                    hv[mm][n][r] = f2bf(__sinf(accp[mm][n][r]));

        WAVE_FENCE();   // prior slice reads (bx or hb) retired before overwrite
        #pragma unroll
        for (int mm = 0; mm < 2; ++mm)
            #pragma unroll
            for (int n = 0; n < 4; ++n) {
                int px = wv * 64 + n * 16 + r16;
                *(s16x4*)(smem + px * 64 + ((mm * 32 + g * 8) ^ ((px & 3) << 4))) = hv[mm][n];
            }
        WAVE_FENCE();   // slice visible

        s16x8 hb[4];
        #pragma unroll
        for (int n = 0; n < 4; ++n) {
            int px = wv * 64 + n * 16 + r16;
            hb[n] = *(const s16x8*)(smem + px * 64 + ((g * 16) ^ ((px & 3) << 4)));
        }

        // issue next L1 pair BEFORE the L2 bulk: its results are ready early
        // in the MFMA pipe so sin[ks+1] overlaps L2[ks]'s pipe time.
        if (ks < 3) {
            #pragma unroll
            for (int mm = 0; mm < 2; ++mm) {
                int m1 = (ks + 1) * 2 + mm;
                f32x4 bv = *(const f32x4*)(b1 + m1 * 16 + g * 4);
                #pragma unroll
                for (int n = 0; n < 4; ++n) accp[mm][n] = bv;
                s16x8 a1 = *(const s16x8*)(W1b + (m1 * 16 + r16) * 32 + g * 8);
                #pragma unroll
                for (int n = 0; n < 4; ++n)
                    accp[mm][n] = __builtin_amdgcn_mfma_f32_16x16x32_bf16(a1, bx[n], accp[mm][n], 0, 0, 0);
            }
        }

        // layer-2 MFMAs for this ks, A-frags in half-batches of 4 (VGPR cap)
        #pragma unroll
        for (int hf = 0; hf < 2; ++hf) {
            s16x8 a2[4];
            #pragma unroll
            for (int mi = 0; mi < 4; ++mi) {
                int m = hf * 4 + mi;
                a2[mi] = *(const s16x8*)(W2b + (m * 16 + r16) * 128 + ks * 32 + g * 8);
            }
            #pragma unroll
            for (int mi = 0; mi < 4; ++mi)
                #pragma unroll
                for (int n = 0; n < 4; ++n)
                    acc2[hf * 4 + mi][n] = __builtin_amdgcn_mfma_f32_16x16x32_bf16(
                        a2[mi], hb[n], acc2[hf * 4 + mi][n], 0, 0, 0);
        }
    }

    // ---- layer 3 fully in registers: x[f][px] = sum_j W3[f][j]*sin(acc2) ----
    float pf0[4] = {0.f, 0.f, 0.f, 0.f};
    float pf1[4] = {0.f, 0.f, 0.f, 0.f};
    float pf2[4] = {0.f, 0.f, 0.f, 0.f};
    #pragma unroll
    for (int m = 0; m < 8; ++m) {
        float s2[4][4];
        #pragma unroll
        for (int n = 0; n < 4; ++n)
            #pragma unroll
            for (int r = 0; r < 4; ++r)
                s2[n][r] = __sinf(acc2[m][n][r]);
        f32x4 w3a = *(const f32x4*)(W3 + 0 * 128 + m * 16 + g * 4);
        f32x4 w3b = *(const f32x4*)(W3 + 1 * 128 + m * 16 + g * 4);
        f32x4 w3c = *(const f32x4*)(W3 + 2 * 128 + m * 16 + g * 4);
        #pragma unroll
        for (int n = 0; n < 4; ++n)
            #pragma unroll
            for (int r = 0; r < 4; ++r) {
                pf0[n] = fmaf(s2[n][r], w3a[r], pf0[n]);
                pf1[n] = fmaf(s2[n][r], w3b[r], pf1[n]);
                pf2[n] = fmaf(s2[n][r], w3c[r], pf2[n]);
            }
    }
    // reduce over the 4 g-groups (lanes r16, r16+16, r16+32, r16+48)
    {
        const float b30 = b3[0], b31 = b3[1], b32 = b3[2];
        float x0 = 0.f, x1 = 0.f, x2 = 0.f;
        #pragma unroll
        for (int n = 0; n < 4; ++n) {
            float v0r = pf0[n]; v0r += __shfl_xor(v0r, 16); v0r += __shfl_xor(v0r, 32);
            float v1r = pf1[n]; v1r += __shfl_xor(v1r, 16); v1r += __shfl_xor(v1r, 32);
            float v2r = pf2[n]; v2r += __shfl_xor(v2r, 16); v2r += __shfl_xor(v2r, 32);
            if (g == n) { x0 = v0r; x1 = v1r; x2 = v2r; }
        }
        // every thread stores its own pixel (tid = wv*64 + g*16 + r16)
        x0 += b30; x1 += b31; x2 += b32;
        const int base = (c * 256 + tid) * 3;
        out0[base + 0] = p[0] + x0;
        out0[base + 1] = p[1] + x1;
        out0[base + 2] = p[2] + x2;
        out1[base + 0] = x0;
        out1[base + 1] = x1;
        out1[base + 2] = x2;
    }
    if (c == 0 && tid == 0) out2[0] = 1.0f;
}

extern "C" void kernel_launch(void* const* d_in, const int* in_sizes, int n_in,
                              void* d_out, int out_size, void* d_ws, size_t ws_size,
                              hipStream_t stream) {
    const float* points    = (const float*)d_in[0];
    const float* encodings = (const float*)d_in[1];
    const float* W1        = (const float*)d_in[2];
    const float* b1        = (const float*)d_in[3];
    const float* W2        = (const float*)d_in[4];
    const float* b2        = (const float*)d_in[5];
    const float* W3        = (const float*)d_in[6];
    const float* b3        = (const float*)d_in[7];
    const int*   complexes = (const int*)d_in[8];

    const int C  = in_sizes[8] / 4;          // 2048
    const int N3 = C * 256 * 3;              // 1,572,864

    float* out0 = (float*)d_out;
    float* out1 = out0 + N3;
    float* out2 = out1 + N3;

    __hip_bfloat16* ws = (__hip_bfloat16*)d_ws;  // needs 40960 B

    NSC_prep_kernel<<<80, 256, 0, stream>>>(W1, W2, ws);
    NSC_59133109732095_kernel<<<C, 256, 0, stream>>>(
        points, encodings, b1, b2, W3, b3, complexes, ws, out0, out1, out2);
}

// Round 11
// 47.153 us; speedup vs baseline: 2.0392x; 1.2536x over previous
//
#include <hip/hip_runtime.h>
#include <hip/hip_bf16.h>

#define ENC 15

typedef __attribute__((ext_vector_type(4))) float f32x4;
typedef __attribute__((ext_vector_type(8))) short s16x8;
typedef __attribute__((ext_vector_type(4))) short s16x4;

static __device__ __forceinline__ short f2bf(float v) {
    __hip_bfloat16 h = __float2bfloat16(v);
    return __builtin_bit_cast(short, h);
}

// Wave-local LDS fence (r9/r10-proven).
#define WAVE_FENCE() do { \
    asm volatile("s_waitcnt lgkmcnt(0)" ::: "memory"); \
    __builtin_amdgcn_sched_barrier(0); \
} while (0)

// ---- weight prep ----
// ws layout (bf16):
//   W1b  [128][32] @ 0      (k padded 18->32), consumed from GLOBAL (only 8
//                            loads/wave — not worth LDS)
//   W2s  [16384]   @ 4096   PRE-SWIZZLED W2 bf16: ws[4096+p] = W2[p ^ s(p)],
//                            s(p) = ((p>>7)&7)<<3  (row-preserving XOR, so a
//                            linear LDS stage + swizzled ds_read = exact W2).
__global__ void NSC_prep_kernel(const float* __restrict__ W1,
                                const float* __restrict__ W2,
                                __hip_bfloat16* __restrict__ ws) {
    int t = blockIdx.x * 256 + threadIdx.x;
    if (t < 4096) {
        int row = t >> 5, k = t & 31;
        float v = (k < 18) ? W1[row * 18 + k] : 0.0f;
        ws[t] = __float2bfloat16(v);
    } else if (t < 20480) {
        int p = t - 4096;                      // bf16 index in [128][128]
        int l = p ^ (((p >> 7) & 7) << 3);     // logical source index
        ws[t] = __float2bfloat16(W2[l]);
    }
}

// One block = one complex = 256 px, 4 waves. r10 ks-pipeline, plus:
//  - W2 staged to LDS (32 KB) once per block, pre-swizzled -> a2 via
//    ds_read_b128, 2-way banked, compiler-pipelined via lgkmcnt (kills the
//    per-ks vmcnt stalls on W2 global loads).
//  - h-slices double-buffered (2 x 16 KB) -> ONE fence per ks (was two).
// LDS map: [0,32768) W2s ; [32768,49152) slice0 (X, then h ks=1,3) ;
//          [49152,65536) slice1 (h ks=0,2).
// Arithmetic bit-identical to r10 (canary: absmax == 0.015625).
__global__ __launch_bounds__(256, 2)
void NSC_59133109732095_kernel(
    const float* __restrict__ points,
    const float* __restrict__ encodings,
    const float* __restrict__ b1,
    const float* __restrict__ b2,
    const float* __restrict__ W3,
    const float* __restrict__ b3,
    const int*   __restrict__ complexes,
    const __hip_bfloat16* __restrict__ ws,
    float* __restrict__ out0,
    float* __restrict__ out1,
    float* __restrict__ out2)
{
    __shared__ __align__(16) char smem[65536];
    char* W2s = smem;            // 32 KB, linear copy of pre-swizzled W2
    char* Xb  = smem + 32768;    // slice0: X rows [256][64 B]

    const int c    = blockIdx.x;
    const int tid  = threadIdx.x;
    const int lane = tid & 63;
    const int wv   = tid >> 6;
    const int g    = lane >> 4;
    const int r16  = lane & 15;

    const __hip_bfloat16* W1b = ws;
    const char* ws2b = (const char*)(ws + 4096);

    // ---- stage W2s: 32 KB, 128 B/thread, loads issue now, hidden by phase0 ----
    s16x8 stg[8];
    #pragma unroll
    for (int i = 0; i < 8; ++i)
        stg[i] = *(const s16x8*)(ws2b + i * 4096 + tid * 16);

    // ---- phase 0: per-thread bilinear interp, pixel = tid (r10-identical) ----
    const int pi = tid >> 4, pj = tid & 15;
    const float ui = (float)pi * (1.0f / 15.0f);
    const float uj = (float)pj * (1.0f / 15.0f);
    const float w00 = (1.0f - ui) * (1.0f - uj), w01 = (1.0f - ui) * uj;
    const float w10 = ui * (1.0f - uj),          w11 = ui * uj;
    const int v0 = complexes[c * 4 + 0], v1 = complexes[c * 4 + 1];
    const int v2 = complexes[c * 4 + 2], v3 = complexes[c * 4 + 3];

    float p[3];
    #pragma unroll
    for (int f = 0; f < 3; ++f)
        p[f] = w00 * points[v0 * 3 + f] + w01 * points[v1 * 3 + f]
             + w10 * points[v2 * 3 + f] + w11 * points[v3 * 3 + f];

    float Xf[18];
    #pragma unroll
    for (int k = 0; k < ENC; ++k)
        Xf[k] = w00 * encodings[v0 * ENC + k] + w01 * encodings[v1 * ENC + k]
              + w10 * encodings[v2 * ENC + k] + w11 * encodings[v3 * ENC + k];
    #pragma unroll
    for (int f = 0; f < 3; ++f) Xf[ENC + f] = __sinf(p[f]);

    // write X row (32 bf16 zero-padded) into slice0
    #pragma unroll
    for (int ch = 0; ch < 4; ++ch) {
        s16x8 v;
        #pragma unroll
        for (int i = 0; i < 8; ++i) {
            int k = ch * 8 + i;
            v[i] = (k < 18) ? f2bf(Xf[k]) : (short)0;
        }
        *(s16x8*)(Xb + tid * 64 + ((ch * 16) ^ ((tid & 3) << 4))) = v;
    }

    // write staged W2 chunks (linear)
    #pragma unroll
    for (int i = 0; i < 8; ++i)
        *(s16x8*)(W2s + i * 4096 + tid * 16) = stg[i];

    __syncthreads();   // W2s + X visible block-wide (single barrier)

    // ---- read X B-frags once into persistent registers ----
    s16x8 bx[4];
    #pragma unroll
    for (int n = 0; n < 4; ++n) {
        int px = wv * 64 + n * 16 + r16;
        bx[n] = *(const s16x8*)(Xb + px * 64 + ((g * 16) ^ ((px & 3) << 4)));
    }

    // ---- init layer-2 accumulators with biases ----
    f32x4 acc2[8][4];
    #pragma unroll
    for (int m = 0; m < 8; ++m) {
        f32x4 bv = *(const f32x4*)(b2 + m * 16 + g * 4);
        #pragma unroll
        for (int n = 0; n < 4; ++n) acc2[m][n] = bv;
    }

    // ---- prologue: layer-1 pair for ks=0 ----
    f32x4 accp[2][4];
    #pragma unroll
    for (int mm = 0; mm < 2; ++mm) {
        f32x4 bv = *(const f32x4*)(b1 + mm * 16 + g * 4);
        #pragma unroll
        for (int n = 0; n < 4; ++n) accp[mm][n] = bv;
        s16x8 a1 = *(const s16x8*)(W1b + (mm * 16 + r16) * 32 + g * 8);
        #pragma unroll
        for (int n = 0; n < 4; ++n)
            accp[mm][n] = __builtin_amdgcn_mfma_f32_16x16x32_bf16(a1, bx[n], accp[mm][n], 0, 0, 0);
    }

    // ---- main ks pipeline (double-buffered h-slices, 1 fence/ks) ----
    #pragma unroll
    for (int ks = 0; ks < 4; ++ks) {
        char* hsl = smem + 32768 + (1 - (ks & 1)) * 16384;  // ks0->slice1, ks1->slice0,...

        // sin+pack current L1 pair
        s16x4 hv[2][4];
        #pragma unroll
        for (int mm = 0; mm < 2; ++mm)
            #pragma unroll
            for (int n = 0; n < 4; ++n)
                #pragma unroll
                for (int r = 0; r < 4; ++r)
                    hv[mm][n][r] = f2bf(__sinf(accp[mm][n][r]));

        #pragma unroll
        for (int mm = 0; mm < 2; ++mm)
            #pragma unroll
            for (int n = 0; n < 4; ++n) {
                int px = wv * 64 + n * 16 + r16;
                *(s16x4*)(hsl + px * 64 + ((mm * 32 + g * 8) ^ ((px & 3) << 4))) = hv[mm][n];
            }
        WAVE_FENCE();   // slice visible (wave-private rows)

        s16x8 hb[4];
        #pragma unroll
        for (int n = 0; n < 4; ++n) {
            int px = wv * 64 + n * 16 + r16;
            hb[n] = *(const s16x8*)(hsl + px * 64 + ((g * 16) ^ ((px & 3) << 4)));
        }

        // issue next L1 pair before the L2 bulk (overlap material)
        if (ks < 3) {
            #pragma unroll
            for (int mm = 0; mm < 2; ++mm) {
                int m1 = (ks + 1) * 2 + mm;
                f32x4 bv = *(const f32x4*)(b1 + m1 * 16 + g * 4);
                #pragma unroll
                for (int n = 0; n < 4; ++n) accp[mm][n] = bv;
                s16x8 a1 = *(const s16x8*)(W1b + (m1 * 16 + r16) * 32 + g * 8);
                #pragma unroll
                for (int n = 0; n < 4; ++n)
                    accp[mm][n] = __builtin_amdgcn_mfma_f32_16x16x32_bf16(a1, bx[n], accp[mm][n], 0, 0, 0);
            }
        }

        // layer-2 MFMAs; a2 from LDS (swizzled ds_read_b128, lgkm-pipelined)
        #pragma unroll
        for (int hf = 0; hf < 2; ++hf) {
            s16x8 a2[4];
            #pragma unroll
            for (int mi = 0; mi < 4; ++mi) {
                int row = (hf * 4 + mi) * 16 + r16;
                int L   = row * 256 + ks * 64 + g * 16;          // logical byte
                a2[mi] = *(const s16x8*)(W2s + (L ^ ((r16 & 7) << 4)));
            }
            #pragma unroll
            for (int mi = 0; mi < 4; ++mi)
                #pragma unroll
                for (int n = 0; n < 4; ++n)
                    acc2[hf * 4 + mi][n] = __builtin_amdgcn_mfma_f32_16x16x32_bf16(
                        a2[mi], hb[n], acc2[hf * 4 + mi][n], 0, 0, 0);
        }
    }

    // ---- layer 3 fully in registers (r10-identical) ----
    float pf0[4] = {0.f, 0.f, 0.f, 0.f};
    float pf1[4] = {0.f, 0.f, 0.f, 0.f};
    float pf2[4] = {0.f, 0.f, 0.f, 0.f};
    #pragma unroll
    for (int m = 0; m < 8; ++m) {
        float s2[4][4];
        #pragma unroll
        for (int n = 0; n < 4; ++n)
            #pragma unroll
            for (int r = 0; r < 4; ++r)
                s2[n][r] = __sinf(acc2[m][n][r]);
        f32x4 w3a = *(const f32x4*)(W3 + 0 * 128 + m * 16 + g * 4);
        f32x4 w3b = *(const f32x4*)(W3 + 1 * 128 + m * 16 + g * 4);
        f32x4 w3c = *(const f32x4*)(W3 + 2 * 128 + m * 16 + g * 4);
        #pragma unroll
        for (int n = 0; n < 4; ++n)
            #pragma unroll
            for (int r = 0; r < 4; ++r) {
                pf0[n] = fmaf(s2[n][r], w3a[r], pf0[n]);
                pf1[n] = fmaf(s2[n][r], w3b[r], pf1[n]);
                pf2[n] = fmaf(s2[n][r], w3c[r], pf2[n]);
            }
    }
    {
        const float b30 = b3[0], b31 = b3[1], b32 = b3[2];
        float x0 = 0.f, x1 = 0.f, x2 = 0.f;
        #pragma unroll
        for (int n = 0; n < 4; ++n) {
            float v0r = pf0[n]; v0r += __shfl_xor(v0r, 16); v0r += __shfl_xor(v0r, 32);
            float v1r = pf1[n]; v1r += __shfl_xor(v1r, 16); v1r += __shfl_xor(v1r, 32);
            float v2r = pf2[n]; v2r += __shfl_xor(v2r, 16); v2r += __shfl_xor(v2r, 32);
            if (g == n) { x0 = v0r; x1 = v1r; x2 = v2r; }
        }
        x0 += b30; x1 += b31; x2 += b32;
        const int base = (c * 256 + tid) * 3;
        out0[base + 0] = p[0] + x0;
        out0[base + 1] = p[1] + x1;
        out0[base + 2] = p[2] + x2;
        out1[base + 0] = x0;
        out1[base + 1] = x1;
        out1[base + 2] = x2;
    }
    if (c == 0 && tid == 0) out2[0] = 1.0f;
}

extern "C" void kernel_launch(void* const* d_in, const int* in_sizes, int n_in,
                              void* d_out, int out_size, void* d_ws, size_t ws_size,
                              hipStream_t stream) {
    const float* points    = (const float*)d_in[0];
    const float* encodings = (const float*)d_in[1];
    const float* W1        = (const float*)d_in[2];
    const float* b1        = (const float*)d_in[3];
    const float* W2        = (const float*)d_in[4];
    const float* b2        = (const float*)d_in[5];
    const float* W3        = (const float*)d_in[6];
    const float* b3        = (const float*)d_in[7];
    const int*   complexes = (const int*)d_in[8];

    const int C  = in_sizes[8] / 4;          // 2048
    const int N3 = C * 256 * 3;              // 1,572,864

    float* out0 = (float*)d_out;
    float* out1 = out0 + N3;
    float* out2 = out1 + N3;

    __hip_bfloat16* ws = (__hip_bfloat16*)d_ws;  // needs 40960 B

    NSC_prep_kernel<<<80, 256, 0, stream>>>(W1, W2, ws);
    NSC_59133109732095_kernel<<<C, 256, 0, stream>>>(
        points, encodings, b1, b2, W3, b3, complexes, ws, out0, out1, out2);
}